// Round 11
// baseline (2371.071 us; speedup 1.0000x reference)
//
#include <hip/hip_runtime.h>
#include <math.h>

// Conv1D(k=2,F=64,relu) -> LSTM1(H=100, relu cell, seq) -> LSTM2 (last) ->
// Dense(3) -> softmax.  B=128, T=2048, T'=2047.
//
// Round-16 = round-15 with the consumer weight-array overflow fixed.
//  r15 NaN root cause: consumer loads 52 h2 GEMM weights into `h2 gw[32]`
//  (unrolled writes gw[0..51]) -> UB clobbers uw -> garbage weights ->
//  cell state explodes -> inf-inf = NaN.  Fix: gw[52] (producer uses 32).
//  Also fixed: bias gather now uses clamped lrt (inactive lanes previously
//  read b1/b2 out of bounds).
//
// Design (unchanged from r15):
//  * r14 layer-split pipeline (128 producer + 128 consumer blocks, 4-slot
//    global h1 ring, agent-scope atomics, r14-proven transport protocol).
//  * Per-chunk (CHK=32) input-projection precompute: conv x -> GEMM
//    z1 = W1^T x (barrier-free, thread=column) -> serial steps are ONLY
//    z[t] + U*h(t-1): thread=(unit,gate), 52 fdot2/step, gates combined
//    across the quad with 3 DPP xor-exchanges (no K-split reduce).
//  * Consumer: stage h1 chunk -> GEMM z2 = W2^T h1 -> serial U2*h2 ->
//    dense+softmax.
//  * Serial h-row reads are wave-uniform -> LDS broadcast (kills r14's
//    12M bank conflicts).  z stored f32.
//  * LDS union 58KB; weights prepacked f16 per-thread (r11-proven).

typedef _Float16 h2 __attribute__((ext_vector_type(2)));

#define TT 2048
#define TP 2047
#define HH 100
#define G4 400
#define FF 64
#define NB 128

#define CHK 32
#define NCHUNK 64            // ceil(2047/32)
#define RINGC 4
#define CHUNK_DW (CHK * 50)  // 1600 dwords per ring slot

#define NPW (400 * 84)       // producer packed h2 (32 gemm + 52 serial)
#define NCW (400 * 104)      // consumer packed h2 (52 gemm + 52 serial)
// ws layout in 4B units
#define WS_FLAGS (NPW + NCW)       // pflag[128], aflag[128]
#define WS_RING  (WS_FLAGS + 256)  // 128 * RINGC * CHUNK_DW dwords

#define FD2(w, xs, acc) acc = __builtin_amdgcn_fdot2(w, xs, acc, false)
#define B2(f) __builtin_bit_cast(h2, f)

// DPP quad_perm: 0xB1 = xor-1, 0x4E = xor-2 (proven r6-r14)
static __device__ __forceinline__ float xswap1(float z) {
    int p = __builtin_amdgcn_update_dpp(0, __builtin_bit_cast(int, z),
                                        0xB1, 0xF, 0xF, true);
    return __builtin_bit_cast(float, p);
}
static __device__ __forceinline__ float xswap2(float z) {
    int p = __builtin_amdgcn_update_dpp(0, __builtin_bit_cast(int, z),
                                        0x4E, 0xF, 0xF, true);
    return __builtin_bit_cast(float, p);
}
static __device__ __forceinline__ float sig(float z) {
    return 1.0f / (1.0f + __expf(-z));
}

// ---------------- prep kernel: pack weights f16 in per-thread order --------
// column for thread rt: c = (rt&3)*100 + (rt>>2)   (gate g = rt&3, unit p)
__global__ void prep_weights(const float* __restrict__ w1, const float* __restrict__ u1,
                             const float* __restrict__ w2, const float* __restrict__ u2,
                             h2* __restrict__ ws)
{
    const int idx = blockIdx.x * 256 + threadIdx.x;
    if (idx >= NPW + NCW) return;
    float lo = 0.f, hi = 0.f;
    if (idx < NPW) {
        const int rt = idx / 84, j = idx % 84;
        const int c = (rt & 3) * HH + (rt >> 2);
        if (j < 32) {                       // GEMM: W1 col, k=2j (k<64)
            const int k = 2 * j;
            lo = w1[k * G4 + c]; hi = w1[(k + 1) * G4 + c];
        } else {                            // serial: U1 col, kk=2(j-32), pad>=100
            const int kk = 2 * (j - 32);
            lo = (kk < HH) ? u1[kk * G4 + c] : 0.f;
            hi = (kk + 1 < HH) ? u1[(kk + 1) * G4 + c] : 0.f;
        }
    } else {
        const int i2 = idx - NPW;
        const int rt = i2 / 104, j = i2 % 104;
        const int c = (rt & 3) * HH + (rt >> 2);
        if (j < 52) {                       // GEMM: W2 col, k=2j, pad>=100
            const int k = 2 * j;
            lo = (k < HH) ? w2[k * G4 + c] : 0.f;
            hi = (k + 1 < HH) ? w2[(k + 1) * G4 + c] : 0.f;
        } else {                            // serial: U2 col
            const int kk = 2 * (j - 52);
            lo = (kk < HH) ? u2[kk * G4 + c] : 0.f;
            hi = (kk + 1 < HH) ? u2[(kk + 1) * G4 + c] : 0.f;
        }
    }
    ws[idx] = h2{(_Float16)lo, (_Float16)hi};
}

// ---------------- main kernel ----------------------------------------------
__global__ __launch_bounds__(512, 2)
void fused_lstm_kernel(const float* __restrict__ s,       // [B,T]
                       const float* __restrict__ conv_w,  // [2,1,F]
                       const float* __restrict__ conv_b,  // [F]
                       const float* __restrict__ b1,
                       const float* __restrict__ b2,
                       const float* __restrict__ dw, const float* __restrict__ db,
                       h2* __restrict__ wpk,              // weights + flags + ring
                       float* __restrict__ out)           // [B,3]
{
    const int tid  = threadIdx.x;
    const int bb   = blockIdx.x;
    const int b    = bb & (NB - 1);
    const bool prod = bb < NB;

    int* pflag = (int*)(wpk + WS_FLAGS) + b;
    int* aflag = (int*)(wpk + WS_FLAGS) + 128 + b;
    unsigned* ring = (unsigned*)(wpk + WS_RING) + (size_t)b * (RINGC * CHUNK_DW);

    // LDS union (58.3KB): z[CHK*400]f32 @0; producer xch/[HR] or consumer h1c/[HR]
    __shared__ __align__(16) unsigned char smem[58368];
    float*     zs  = (float*)smem;                       // [CHK][400] f32
    _Float16*  xch = (_Float16*)(smem + 51200);          // P: [CHK][64]
    _Float16*  HRp = (_Float16*)(smem + 55296);          // P: [2][104] h1 ring
    _Float16*  h1c = (_Float16*)(smem + 51200);          // C: [CHK][104]
    _Float16*  HRc = (_Float16*)(smem + 57856);          // C: [2][104] h2 ring

    const int active = tid < 400;
    const int lrt = active ? tid : 0;
    const int gg = tid & 3;                              // gate
    const int pp = tid >> 2;                             // unit

    if (prod) {
        if (tid < 104) ((unsigned*)HRp)[tid] = 0u;       // h(-1)=0 + pad
    } else {
        if (tid < 104) ((unsigned*)HRc)[tid] = 0u;
        if (tid < CHK * 2) {                             // h1c pad dwords [50,52)/row
            ((unsigned*)h1c)[(tid >> 1) * 52 + 50 + (tid & 1)] = 0u;
        }
    }

    // weights into registers (consumer needs gw[52]; producer uses first 32)
    h2 gw[52]; h2 uw[52];
    float bias = 0.f;
    {
        const int cidx = (lrt & 3) * HH + (lrt >> 2);    // in-bounds for all lanes
        if (prod) {
            const float4* w4 = (const float4*)(wpk + (size_t)lrt * 84);
#pragma unroll
            for (int r = 0; r < 8; ++r) {
                const float4 v = w4[r];
                gw[4*r+0]=B2(v.x); gw[4*r+1]=B2(v.y); gw[4*r+2]=B2(v.z); gw[4*r+3]=B2(v.w);
            }
#pragma unroll
            for (int r = 0; r < 13; ++r) {
                const float4 v = w4[8 + r];
                uw[4*r+0]=B2(v.x); uw[4*r+1]=B2(v.y); uw[4*r+2]=B2(v.z); uw[4*r+3]=B2(v.w);
            }
            bias = b1[cidx];
        } else {
            const float4* w4 = (const float4*)(wpk + NPW + (size_t)lrt * 104);
#pragma unroll
            for (int r = 0; r < 13; ++r) {
                const float4 v = w4[r];
                gw[4*r+0]=B2(v.x); gw[4*r+1]=B2(v.y); gw[4*r+2]=B2(v.z); gw[4*r+3]=B2(v.w);
            }
#pragma unroll
            for (int r = 0; r < 13; ++r) {
                const float4 v = w4[13 + r];
                uw[4*r+0]=B2(v.x); uw[4*r+1]=B2(v.y); uw[4*r+2]=B2(v.z); uw[4*r+3]=B2(v.w);
            }
            bias = b2[cidx];
        }
    }
    // conv constants (producer, all 512 threads; f = tid&63)
    float cv0 = 0.f, cv1 = 0.f, cb0 = 0.f;
    if (prod) {
        const int f = tid & 63;
        cv0 = conv_w[f]; cv1 = conv_w[FF + f]; cb0 = conv_b[f];
    }
    __syncthreads();                                     // (A)

    float c = 0.0f;                                      // cell state

    if (prod) {
        // ================= PRODUCER: conv + GEMM z1 + serial LSTM1 ==========
        const float* sb = s + (size_t)b * TT;
        for (int k = 0; k < NCHUNK; ++k) {
            const int t0  = k * CHK;
            const int csz = (TP - t0 < CHK) ? (TP - t0) : CHK;
            if (tid == 0 && k >= RINGC) {                // ring credit
                int g = 0;
                while (__hip_atomic_load(aflag, __ATOMIC_ACQUIRE,
                                         __HIP_MEMORY_SCOPE_AGENT) < k - (RINGC - 1)
                       && g < 50000000) { ++g; __builtin_amdgcn_s_sleep(8); }
            }
            // conv: x[t] for chunk (wave-uniform s reads)
#pragma unroll
            for (int j = 0; j < 4; ++j) {
                const int e = j * 512 + tid;
                const int lt = e >> 6, f = e & 63;
                if (lt < csz) {
                    const float sv0 = sb[t0 + lt], sv1 = sb[t0 + lt + 1];
                    xch[lt * 64 + f] =
                        (_Float16)fmaxf(fmaf(sv0, cv0, fmaf(sv1, cv1, cb0)), 0.f);
                }
            }
            __syncthreads();                             // x ready
            // GEMM: z1[lt][tid] = W1col . x[lt]
            if (active) {
                for (int lt = 0; lt < csz; ++lt) {
                    const float4* xr = (const float4*)(xch + lt * 64);
                    float za = 0.f, zb = 0.f;
#pragma unroll
                    for (int r = 0; r < 8; ++r) {
                        const float4 v = xr[r];
                        FD2(gw[4*r+0], B2(v.x), za); FD2(gw[4*r+1], B2(v.y), zb);
                        FD2(gw[4*r+2], B2(v.z), za); FD2(gw[4*r+3], B2(v.w), zb);
                    }
                    zs[lt * 400 + tid] = za + zb;
                }
            }
            __syncthreads();                             // z ready
            // serial: 32 steps of z + U1*h
            for (int lt = 0; lt < csz; ++lt) {
                const int t = t0 + lt;
                if (active) {
                    const float4* hr4 = (const float4*)(HRp + (t & 1) * 104);
                    float za = 0.f, zb = 0.f;
#pragma unroll
                    for (int r = 0; r < 13; ++r) {
                        const float4 v = hr4[r];
                        FD2(uw[4*r+0], B2(v.x), za); FD2(uw[4*r+1], B2(v.y), zb);
                        FD2(uw[4*r+2], B2(v.z), za); FD2(uw[4*r+3], B2(v.w), zb);
                    }
                    const float zown = za + zb + zs[lt * 400 + tid] + bias;
                    const float v1 = xswap1(zown);
                    const float v2 = xswap2(zown);
                    const float v3 = xswap2(v1);
                    const float zi = gg==0 ? zown : gg==1 ? v1 : gg==2 ? v2 : v3;
                    const float zf = gg==1 ? zown : gg==0 ? v1 : gg==3 ? v2 : v3;
                    const float zg = gg==2 ? zown : gg==3 ? v1 : gg==0 ? v2 : v3;
                    const float zo = gg==3 ? zown : gg==2 ? v1 : gg==1 ? v2 : v3;
                    c = fmaf(sig(zf), c, sig(zi) * fmaxf(zg, 0.f));
                    const float h = sig(zo) * fmaxf(c, 0.f);
                    if (gg == 0) {
                        const _Float16 hq = (_Float16)h;
                        HRp[((t & 1) ^ 1) * 104 + pp] = hq;
                        const unsigned hb = (unsigned)__builtin_bit_cast(unsigned short, hq);
                        const unsigned prt =
                            (unsigned)__builtin_amdgcn_ds_swizzle((int)hb, 0x101F) & 0xFFFFu;
                        if (!(pp & 1))
                            __hip_atomic_store(ring + ((t >> 5) & 3) * CHUNK_DW
                                                    + (t & 31) * 50 + (pp >> 1),
                                               hb | (prt << 16), __ATOMIC_RELAXED,
                                               __HIP_MEMORY_SCOPE_AGENT);
                    }
                }
                __syncthreads();                         // per-step barrier
            }
            asm volatile("s_waitcnt vmcnt(0)" ::: "memory");
            __syncthreads();                             // ring drained
            if (tid == 0)
                __hip_atomic_fetch_add(pflag, 1, __ATOMIC_RELEASE,
                                       __HIP_MEMORY_SCOPE_AGENT);
        }
    } else {
        // ================= CONSUMER: stage + GEMM z2 + serial LSTM2 =========
        for (int k = 0; k < NCHUNK; ++k) {
            const int t0  = k * CHK;
            const int csz = (TP - t0 < CHK) ? (TP - t0) : CHK;
            if (tid == 0) {                              // wait producer chunk
                int g = 0;
                while (__hip_atomic_load(pflag, __ATOMIC_ACQUIRE,
                                         __HIP_MEMORY_SCOPE_AGENT) < k + 1
                       && g < 50000000) { ++g; __builtin_amdgcn_s_sleep(8); }
            }
            __syncthreads();                             // chunk ready
            unsigned* gsrc = ring + (k & 3) * CHUNK_DW;
            for (int d = tid; d < csz * 50; d += 512)
                ((unsigned*)h1c)[(d / 50) * 52 + (d % 50)] =
                    __hip_atomic_load(gsrc + d, __ATOMIC_RELAXED,
                                      __HIP_MEMORY_SCOPE_AGENT);
            __syncthreads();                             // staged
            if (tid == 0)
                __hip_atomic_fetch_add(aflag, 1, __ATOMIC_RELAXED,
                                       __HIP_MEMORY_SCOPE_AGENT);
            // GEMM: z2[lt][tid] = W2col . h1[lt]
            if (active) {
                for (int lt = 0; lt < csz; ++lt) {
                    const float4* xr = (const float4*)(h1c + lt * 104);
                    float za = 0.f, zb = 0.f;
#pragma unroll
                    for (int r = 0; r < 13; ++r) {
                        const float4 v = xr[r];
                        FD2(gw[4*r+0], B2(v.x), za); FD2(gw[4*r+1], B2(v.y), zb);
                        FD2(gw[4*r+2], B2(v.z), za); FD2(gw[4*r+3], B2(v.w), zb);
                    }
                    zs[lt * 400 + tid] = za + zb;
                }
            }
            __syncthreads();                             // z2 ready
            // serial: 32 steps of z2 + U2*h2
            for (int lt = 0; lt < csz; ++lt) {
                const int t = t0 + lt;
                if (active) {
                    const float4* hr4 = (const float4*)(HRc + (t & 1) * 104);
                    float za = 0.f, zb = 0.f;
#pragma unroll
                    for (int r = 0; r < 13; ++r) {
                        const float4 v = hr4[r];
                        FD2(uw[4*r+0], B2(v.x), za); FD2(uw[4*r+1], B2(v.y), zb);
                        FD2(uw[4*r+2], B2(v.z), za); FD2(uw[4*r+3], B2(v.w), zb);
                    }
                    const float zown = za + zb + zs[lt * 400 + tid] + bias;
                    const float v1 = xswap1(zown);
                    const float v2 = xswap2(zown);
                    const float v3 = xswap2(v1);
                    const float zi = gg==0 ? zown : gg==1 ? v1 : gg==2 ? v2 : v3;
                    const float zf = gg==1 ? zown : gg==0 ? v1 : gg==3 ? v2 : v3;
                    const float zg = gg==2 ? zown : gg==3 ? v1 : gg==0 ? v2 : v3;
                    const float zo = gg==3 ? zown : gg==2 ? v1 : gg==1 ? v2 : v3;
                    c = fmaf(sig(zf), c, sig(zi) * fmaxf(zg, 0.f));
                    const float h = sig(zo) * fmaxf(c, 0.f);
                    if (gg == 0)
                        HRc[((t & 1) ^ 1) * 104 + pp] = (_Float16)h;
                }
                __syncthreads();                         // per-step barrier
            }
        }

        // final h2(t=2046) in HRc slot ((2046&1)^1)=1
        if (tid == 0) {
            float l[3];
#pragma unroll
            for (int a = 0; a < 3; ++a) {
                float acc = db[a];
                for (int j = 0; j < HH; ++j)
                    acc = fmaf((float)HRc[104 + j], dw[j * 3 + a], acc);
                l[a] = acc;
            }
            const float m = fmaxf(l[0], fmaxf(l[1], l[2]));
            const float e0 = __expf(l[0] - m), e1 = __expf(l[1] - m), e2 = __expf(l[2] - m);
            const float inv = 1.0f / (e0 + e1 + e2);
            out[b * 3 + 0] = e0 * inv;
            out[b * 3 + 1] = e1 * inv;
            out[b * 3 + 2] = e2 * inv;
        }
    }
}

// ---------------- launch ----------------------------------------------------
extern "C" void kernel_launch(void* const* d_in, const int* in_sizes, int n_in,
                              void* d_out, int out_size, void* d_ws, size_t ws_size,
                              hipStream_t stream) {
    const float* s      = (const float*)d_in[0];
    const float* conv_w = (const float*)d_in[1];
    const float* conv_b = (const float*)d_in[2];
    const float* w1     = (const float*)d_in[3];
    const float* u1     = (const float*)d_in[4];
    const float* b1     = (const float*)d_in[5];
    const float* w2     = (const float*)d_in[6];
    const float* u2     = (const float*)d_in[7];
    const float* b2     = (const float*)d_in[8];
    const float* dw     = (const float*)d_in[9];
    const float* db     = (const float*)d_in[10];

    h2* ws = (h2*)d_ws;
    hipMemsetAsync((void*)((int*)(ws + WS_FLAGS)), 0, 256 * sizeof(int), stream);
    const int nh2 = NPW + NCW;
    prep_weights<<<(nh2 + 255) / 256, 256, 0, stream>>>(w1, u1, w2, u2, ws);
    fused_lstm_kernel<<<256, 512, 0, stream>>>(
        s, conv_w, conv_b, b1, b2, dw, db, ws, (float*)d_out);
}

// Round 12
// 1856.711 us; speedup vs baseline: 1.2770x; 1.2770x over previous
//
#include <hip/hip_runtime.h>
#include <math.h>

// Conv1D(k=2,F=64,relu) -> LSTM1(H=100, relu cell, seq) -> LSTM2 (last) ->
// Dense(3) -> softmax.  B=128, T=2048, T'=2047.
//
// Round-17 = r14 structure (proven 1879us layer-split pipeline) with the
// per-thread mapping changed to (unit p, gate-pair g2, K-half kh) on BOTH
// roles to cut issued fdot2 (r16 post-mortem: serial step is issue+ILP
// bound; r16's z-precompute kept flops ~equal and lost ILP -> +26%).
//  * producer: K=[x64|h1(100)]=164 -> two 88-half K-halves (6 pad each).
//    2 gates x 44 h2 = 88 fdot2/step (was 96), 4 chains of 22.
//    X1 operand row 176 halves: [half0: orig 0..81 +pad6 | half1: orig
//    82..163 +pad6].  conv writes x[f] at f; h1[p] at 64+p (p<18) else p+70.
//  * consumer: K-half0 = staged h1 row (104 halves: 100+pad4), K-half1 =
//    h2 recurrence ring row.  12 float4 + float2 tail = 100 fdot2/step
//    (was 112), 4 chains of 25.  Lane kh selects base pointer (r14 idiom).
//  * reduction: psum2 (DPP xor-1) over kh + xswap2 (DPP xor-2) gate-pair
//    exchange -- the r12-consumer-proven pattern; all 4 quad lanes compute
//    the cell redundantly; lane (rt&3)==0 writes h (+ring pack, r14 proto).
//  * ring transport / conv wave / chunk handshake / barriers: r14 verbatim.

typedef _Float16 h2 __attribute__((ext_vector_type(2)));

#define TT 2048
#define TP 2047
#define HH 100
#define G4 400
#define FF 64
#define NB 128

#define X1R 176              // producer operand row halves (2x88)
#define CBQ 104              // consumer row halves (100 + pad4)
#define NPW (400 * 88)       // producer packed h2
#define NCW (400 * 100)      // consumer packed h2
#define CHK 64
#define NCHUNK 32
#define RINGC 4
#define CHUNK_DW (CHK * 50)  // 3200 dwords per ring slot

// ws layout in 4B units
#define WS_FLAGS (NPW + NCW)       // pflag[128], aflag[128]
#define WS_RING  (WS_FLAGS + 256)  // 128 * RINGC * CHUNK_DW dwords

#define FD2(w, xs, acc) acc = __builtin_amdgcn_fdot2(w, xs, acc, false)
#define B2(f) __builtin_bit_cast(h2, f)

// DPP quad_perm: 0xB1 = xor-1, 0x4E = xor-2 (proven r6-r16)
static __device__ __forceinline__ float psum2(float z) {
    int p = __builtin_amdgcn_update_dpp(0, __builtin_bit_cast(int, z),
                                        0xB1, 0xF, 0xF, true);
    return z + __builtin_bit_cast(float, p);
}
static __device__ __forceinline__ float xswap2(float z) {
    int p = __builtin_amdgcn_update_dpp(0, __builtin_bit_cast(int, z),
                                        0x4E, 0xF, 0xF, true);
    return __builtin_bit_cast(float, p);
}
static __device__ __forceinline__ float sig(float z) {
    return 1.0f / (1.0f + __expf(-z));
}

// ---------------- prep kernel: pack weights f16 in per-thread order --------
// thread rt = (p<<2)|(g2<<1)|kh ; gates cL=(2*g2)*100+p, cH=cL+100.
// pack: float4 j = (a_{2j}, b_{2j}, a_{2j+1}, b_{2j+1})
__global__ void prep_weights(const float* __restrict__ w1, const float* __restrict__ u1,
                             const float* __restrict__ w2, const float* __restrict__ u2,
                             h2* __restrict__ ws)
{
    const int idx = blockIdx.x * 256 + threadIdx.x;
    if (idx >= NPW + NCW) return;
    float lo = 0.f, hi = 0.f;
    if (idx < NPW) {
        // producer: 88 h2/thread = 22 float4
        const int rt = idx / 88, r = idx % 88;
        const int qq = (r >> 2) * 2 + ((r & 3) >> 1);   // h2 pair index 0..43
        const int gs = r & 1;                           // 0 -> cL, 1 -> cH
        const int p = rt >> 2, g2 = (rt >> 1) & 1, kh = rt & 1;
        const int col = (2 * g2 + gs) * HH + p;
        const int E0 = 2 * qq;                          // in-half elem
#pragma unroll
        for (int e = 0; e < 2; ++e) {
            const int E = E0 + e;
            float v = 0.f;
            if (E < 82) {
                const int k = kh * 82 + E;              // orig combined-K index
                v = (k < FF) ? w1[k * G4 + col] : u1[(k - FF) * G4 + col];
            }
            if (e == 0) lo = v; else hi = v;
        }
    } else {
        // consumer: 100 h2/thread = 25 float4
        const int i2 = idx - NPW;
        const int rt = i2 / 100, r = i2 % 100;
        const int qq = (r >> 2) * 2 + ((r & 3) >> 1);   // 0..49
        const int gs = r & 1;
        const int p = rt >> 2, g2 = (rt >> 1) & 1, kh = rt & 1;
        const int col = (2 * g2 + gs) * HH + p;
        const int k0 = 2 * qq;
        const float* M = kh ? u2 : w2;
        lo = M[k0 * G4 + col];
        hi = M[(k0 + 1) * G4 + col];
    }
    ws[idx] = h2{(_Float16)lo, (_Float16)hi};
}

// ---------------- main kernel ----------------------------------------------
__global__ __launch_bounds__(512, 2)
void fused_lstm_kernel(const float* __restrict__ s,       // [B,T]
                       const float* __restrict__ conv_w,  // [2,1,F]
                       const float* __restrict__ conv_b,  // [F]
                       const float* __restrict__ b1,
                       const float* __restrict__ b2,
                       const float* __restrict__ dw, const float* __restrict__ db,
                       h2* __restrict__ wpk,              // weights + flags + ring
                       float* __restrict__ out)           // [B,3]
{
    const int tid  = threadIdx.x;
    const int bb   = blockIdx.x;
    const int b    = bb & (NB - 1);
    const bool prod = bb < NB;

    int* pflag = (int*)(wpk + WS_FLAGS) + b;
    int* aflag = (int*)(wpk + WS_FLAGS) + 128 + b;
    unsigned* ring = (unsigned*)(wpk + WS_RING) + (size_t)b * (RINGC * CHUNK_DW);

    __shared__ float s_buf[TT];                        // producer only
    __shared__ __align__(16) _Float16 X1[2 * X1R];     // producer operand ring
    __shared__ __align__(16) _Float16 CB[CHK * CBQ];   // consumer staged chunk
    __shared__ __align__(16) _Float16 HR[2 * CBQ];     // consumer h2 ring

    if (prod) {
        for (int i = tid; i < TT; i += 512) s_buf[i] = s[(size_t)b * TT + i];
        if (tid < X1R) ((unsigned*)X1)[tid] = 0u;      // both slots zero (pads stay 0)
    } else {
        if (tid < CBQ) ((unsigned*)HR)[tid] = 0u;      // 2*104 halves = 104 dwords
        if (tid < CHK * 2)                             // CB pad dwords [50,52)/row
            ((unsigned*)CB)[(tid >> 1) * 52 + 50 + (tid & 1)] = 0u;
    }
    __syncthreads();                                   // (A)

    if (prod) {
        // ================= PRODUCER block: conv + LSTM1 =================
        if (tid < 448) {
            const int rt = tid;
            const int active = rt < 400;
            const int lrt = active ? rt : 0;
            const int p  = lrt >> 2;
            const int g2 = (lrt >> 1) & 1;
            const int kh = lrt & 1;
            const int cL = (2 * g2) * HH + p;

            h2 wa[44], wb[44];
            {
                const float4* w4 = (const float4*)(wpk + (size_t)lrt * 88);
#pragma unroll
                for (int j = 0; j < 22; ++j) {
                    const float4 v = w4[j];
                    wa[2*j]   = B2(v.x); wb[2*j]   = B2(v.y);
                    wa[2*j+1] = B2(v.z); wb[2*j+1] = B2(v.w);
                }
            }
            const float bL = b1[cL], bH = b1[cL + HH];
            const int hoff = (p < 18) ? (64 + p) : (p + 70);  // h1[p] slot offset
            __syncthreads();                           // (B)

            float c = 0.0f;
            for (int t = 0; t < TP; ++t) {
                if ((t & 63) == 0) {                   // chunk start: ring credit
                    const int k = t >> 6;
                    if (tid == 0 && k >= RINGC) {
                        int g = 0;
                        while (__hip_atomic_load(aflag, __ATOMIC_ACQUIRE,
                                                 __HIP_MEMORY_SCOPE_AGENT) < k - (RINGC - 1)
                               && g < 50000000) { ++g; __builtin_amdgcn_s_sleep(8); }
                    }
                    __syncthreads();
                }
                if (active) {
                    _Float16* cur = X1 + (t & 1) * X1R;
                    _Float16* nx1 = X1 + ((t & 1) ^ 1) * X1R;
                    float za0 = 0.f, za1 = 0.f, zb0 = 0.f, zb1 = 0.f;
                    const float4* vb = (const float4*)(cur + kh * 88);
#pragma unroll
                    for (int r2 = 0; r2 < 11; ++r2) {
                        const float4 v = vb[r2];
                        FD2(wa[4*r2+0], B2(v.x), za0); FD2(wb[4*r2+0], B2(v.x), zb0);
                        FD2(wa[4*r2+1], B2(v.y), za1); FD2(wb[4*r2+1], B2(v.y), zb1);
                        FD2(wa[4*r2+2], B2(v.z), za0); FD2(wb[4*r2+2], B2(v.z), zb0);
                        FD2(wa[4*r2+3], B2(v.w), za1); FD2(wb[4*r2+3], B2(v.w), zb1);
                    }
                    const float zaS = psum2(za0 + za1) + bL;
                    const float zbS = psum2(zb0 + zb1) + bH;
                    const float oa = xswap2(zaS), ob = xswap2(zbS);
                    const float zi = g2 ? oa  : zaS;
                    const float zf = g2 ? ob  : zbS;
                    const float zg = g2 ? zaS : oa;
                    const float zo = g2 ? zbS : ob;
                    c = fmaf(sig(zf), c, sig(zi) * fmaxf(zg, 0.f));
                    const float h = sig(zo) * fmaxf(c, 0.f);
                    if ((rt & 3) == 0) {
                        const _Float16 hq = (_Float16)h;
                        nx1[hoff] = hq;                // h1 for LSTM1(t+1)
                        const unsigned hb = (unsigned)__builtin_bit_cast(unsigned short, hq);
                        const unsigned prt =
                            (unsigned)__builtin_amdgcn_ds_swizzle((int)hb, 0x101F) & 0xFFFFu;
                        if (!(p & 1))
                            __hip_atomic_store(ring + ((t >> 6) & 3) * CHUNK_DW
                                                    + (t & 63) * 50 + (p >> 1),
                                               hb | (prt << 16), __ATOMIC_RELAXED,
                                               __HIP_MEMORY_SCOPE_AGENT);
                    }
                    if (((t & 63) == 63) || (t == TP - 1))
                        asm volatile("s_waitcnt vmcnt(0)" ::: "memory");
                }
                __syncthreads();                       // (C) one per step
                if (tid == 0 && (((t & 63) == 63) || (t == TP - 1)))
                    __hip_atomic_fetch_add(pflag, 1, __ATOMIC_RELEASE,
                                           __HIP_MEMORY_SCOPE_AGENT);
            }
        } else {
            // conv wave: threads 448-511, one filter each
            const int f = tid - 448;
            const float cv0 = conv_w[f], cv1 = conv_w[FF + f], cb0 = conv_b[f];
            X1[f] = (_Float16)fmaxf(fmaf(s_buf[0], cv0, fmaf(s_buf[1], cv1, cb0)), 0.f);
            __syncthreads();                           // (B)
            for (int t = 0; t < TP; ++t) {
                if ((t & 63) == 0) __syncthreads();    // chunk-start companion
                if (t + 1 < TP) {
                    _Float16* nx1 = X1 + ((t & 1) ^ 1) * X1R;
                    nx1[f] = (_Float16)fmaxf(
                        fmaf(s_buf[t + 1], cv0, fmaf(s_buf[t + 2], cv1, cb0)), 0.f);
                }
                __syncthreads();                       // (C)
            }
        }
    } else {
        // ================= CONSUMER block: LSTM2 + dense + softmax ==========
        if (tid < 448) {
            const int rt = tid;
            const int active = rt < 400;
            const int lrt = active ? rt : 0;
            const int p  = lrt >> 2;
            const int g2 = (lrt >> 1) & 1;
            const int kh = lrt & 1;
            const int cL = (2 * g2) * HH + p;

            h2 wa[50], wb[50];
            {
                const float4* w4 = (const float4*)(wpk + NPW + (size_t)lrt * 100);
#pragma unroll
                for (int j = 0; j < 25; ++j) {
                    const float4 v = w4[j];
                    wa[2*j]   = B2(v.x); wb[2*j]   = B2(v.y);
                    wa[2*j+1] = B2(v.z); wb[2*j+1] = B2(v.w);
                }
            }
            const float bL = b2[cL], bH = b2[cL + HH];
            __syncthreads();                           // (B)

            float c = 0.0f;
            for (int k = 0; k < NCHUNK; ++k) {
                if (tid == 0) {                        // wait for producer chunk k
                    int g = 0;
                    while (__hip_atomic_load(pflag, __ATOMIC_ACQUIRE,
                                             __HIP_MEMORY_SCOPE_AGENT) < k + 1
                           && g < 50000000) { ++g; __builtin_amdgcn_s_sleep(8); }
                }
                __syncthreads();                       // chunk ready
                const int csz = (TP - (k << 6) < CHK) ? (TP - (k << 6)) : CHK;
                unsigned* gsrc = ring + (k & 3) * CHUNK_DW;
                for (int d = tid; d < csz * 50; d += 448)
                    ((unsigned*)CB)[(d / 50) * 52 + (d % 50)] =
                        __hip_atomic_load(gsrc + d, __ATOMIC_RELAXED,
                                          __HIP_MEMORY_SCOPE_AGENT);
                __syncthreads();                       // staged
                if (tid == 0)
                    __hip_atomic_fetch_add(aflag, 1, __ATOMIC_RELAXED,
                                           __HIP_MEMORY_SCOPE_AGENT);
                for (int lt = 0; lt < csz; ++lt) {
                    const int t = (k << 6) + lt;
                    if (active) {
                        const _Float16* base = kh ? (HR + (t & 1) * CBQ)
                                                  : (CB + lt * CBQ);
                        float za0 = 0.f, za1 = 0.f, zb0 = 0.f, zb1 = 0.f;
                        const float4* vb = (const float4*)base;
#pragma unroll
                        for (int r2 = 0; r2 < 12; ++r2) {
                            const float4 v = vb[r2];
                            FD2(wa[4*r2+0], B2(v.x), za0); FD2(wb[4*r2+0], B2(v.x), zb0);
                            FD2(wa[4*r2+1], B2(v.y), za1); FD2(wb[4*r2+1], B2(v.y), zb1);
                            FD2(wa[4*r2+2], B2(v.z), za0); FD2(wb[4*r2+2], B2(v.z), zb0);
                            FD2(wa[4*r2+3], B2(v.w), za1); FD2(wb[4*r2+3], B2(v.w), zb1);
                        }
                        {                              // tail halves 96..99
                            const float2 tv = *(const float2*)(base + 96);
                            FD2(wa[48], B2(tv.x), za0); FD2(wb[48], B2(tv.x), zb0);
                            FD2(wa[49], B2(tv.y), za1); FD2(wb[49], B2(tv.y), zb1);
                        }
                        const float zaS = psum2(za0 + za1) + bL;
                        const float zbS = psum2(zb0 + zb1) + bH;
                        const float oa = xswap2(zaS), ob = xswap2(zbS);
                        const float zi = g2 ? oa  : zaS;
                        const float zf = g2 ? ob  : zbS;
                        const float zg = g2 ? zaS : oa;
                        const float zo = g2 ? zbS : ob;
                        c = fmaf(sig(zf), c, sig(zi) * fmaxf(zg, 0.f));
                        const float h = sig(zo) * fmaxf(c, 0.f);
                        if ((rt & 3) == 0)
                            HR[((t & 1) ^ 1) * CBQ + p] = (_Float16)h;
                    }
                    __syncthreads();                   // (C)
                }
            }

            // final h2(t=2046) was written into slot ((2046&1)^1)=1
            if (rt == 0) {
                float l[3];
#pragma unroll
                for (int a = 0; a < 3; ++a) {
                    float acc = db[a];
                    for (int j = 0; j < HH; ++j)
                        acc = fmaf((float)HR[CBQ + j], dw[j * 3 + a], acc);
                    l[a] = acc;
                }
                const float m = fmaxf(l[0], fmaxf(l[1], l[2]));
                const float e0 = __expf(l[0] - m), e1 = __expf(l[1] - m), e2 = __expf(l[2] - m);
                const float inv = 1.0f / (e0 + e1 + e2);
                out[b * 3 + 0] = e0 * inv;
                out[b * 3 + 1] = e1 * inv;
                out[b * 3 + 2] = e2 * inv;
            }
        } else {
            // threads 448-511: barrier companions
            __syncthreads();                           // (B)
            for (int k = 0; k < NCHUNK; ++k) {
                __syncthreads();                       // chunk ready
                const int csz = (TP - (k << 6) < CHK) ? (TP - (k << 6)) : CHK;
                __syncthreads();                       // staged
                for (int lt = 0; lt < csz; ++lt)
                    __syncthreads();                   // (C)
            }
        }
    }
}

// ---------------- launch ----------------------------------------------------
extern "C" void kernel_launch(void* const* d_in, const int* in_sizes, int n_in,
                              void* d_out, int out_size, void* d_ws, size_t ws_size,
                              hipStream_t stream) {
    const float* s      = (const float*)d_in[0];
    const float* conv_w = (const float*)d_in[1];
    const float* conv_b = (const float*)d_in[2];
    const float* w1     = (const float*)d_in[3];
    const float* u1     = (const float*)d_in[4];
    const float* b1     = (const float*)d_in[5];
    const float* w2     = (const float*)d_in[6];
    const float* u2     = (const float*)d_in[7];
    const float* b2     = (const float*)d_in[8];
    const float* dw     = (const float*)d_in[9];
    const float* db     = (const float*)d_in[10];

    h2* ws = (h2*)d_ws;
    hipMemsetAsync((void*)((int*)(ws + WS_FLAGS)), 0, 256 * sizeof(int), stream);
    const int nh2 = NPW + NCW;
    prep_weights<<<(nh2 + 255) / 256, 256, 0, stream>>>(w1, u1, w2, u2, ws);
    fused_lstm_kernel<<<256, 512, 0, stream>>>(
        s, conv_w, conv_b, b1, b2, dw, db, ws, (float*)d_out);
}